// Round 2
// baseline (1014.340 us; speedup 1.0000x reference)
//
#include <hip/hip_runtime.h>
#include <hip/hip_bf16.h>

// Problem constants (fixed by setup_inputs)
#define TQ   2048
#define TKV  2048
#define NB   2
#define NH   16
#define HD   64
#define CE   1024          // n_embd
#define MQ   (NB*TQ)       // 4096 rows

typedef __bf16 bf16_t;
typedef __bf16 bf16x4_t __attribute__((ext_vector_type(4)));
typedef __bf16 bf16x8_t __attribute__((ext_vector_type(8)));
typedef float  f32x4_t  __attribute__((ext_vector_type(4)));

#define MFMA16(a,b,c) __builtin_amdgcn_mfma_f32_16x16x32_bf16((a),(b),(c),0,0,0)

__device__ __forceinline__ void gload16(const void* g, void* l) {
    __builtin_amdgcn_global_load_lds(
        (__attribute__((address_space(1))) void*)(void*)g,
        (__attribute__((address_space(3))) void*)l, 16, 0, 0);
}

// ---------------- f32 -> (hi,lo) bf16 split, vectorized x4 ----------------
__global__ __launch_bounds__(256) void cvt_split(const float* __restrict__ x,
                                                 bf16_t* __restrict__ hi,
                                                 bf16_t* __restrict__ lo, int n4) {
    int i = blockIdx.x * blockDim.x + threadIdx.x;
    int stride = gridDim.x * blockDim.x;
    for (; i < n4; i += stride) {
        f32x4_t v = ((const f32x4_t*)x)[i];
        bf16x4_t h, l;
#pragma unroll
        for (int j = 0; j < 4; j++) {
            h[j] = (bf16_t)v[j];
            l[j] = (bf16_t)(v[j] - (float)h[j]);
        }
        ((bf16x4_t*)hi)[i] = h;
        ((bf16x4_t*)lo)[i] = l;
    }
}

// ---- weight transpose+split: W f32 [K][N] -> Wh,Wl bf16 [N][K] ----
__global__ __launch_bounds__(256) void wsplit_t(const float* __restrict__ W,
                                                bf16_t* __restrict__ Wh,
                                                bf16_t* __restrict__ Wl, int K, int N) {
    __shared__ float t[32][33];
    int tx = threadIdx.x, ty = threadIdx.y;
    int n0 = blockIdx.x * 32, k0 = blockIdx.y * 32;
#pragma unroll
    for (int j = 0; j < 4; j++)
        t[ty + 8*j][tx] = W[(size_t)(k0 + ty + 8*j) * N + n0 + tx];
    __syncthreads();
#pragma unroll
    for (int j = 0; j < 4; j++) {
        float v = t[tx][ty + 8*j];
        bf16_t h = (bf16_t)v;
        Wh[(size_t)(n0 + ty + 8*j) * K + k0 + tx] = h;
        Wl[(size_t)(n0 + ty + 8*j) * K + k0 + tx] = (bf16_t)(v - (float)h);
    }
}

// ---- V transpose: kv_hi bf16 [B*Tkv][2048] (v = cols 1024..) -> VT [B*H][64][Tkv] ----
__global__ __launch_bounds__(256) void vtrans(const bf16_t* __restrict__ KVm,
                                              bf16_t* __restrict__ VT) {
    __shared__ bf16_t t[32][33];
    int tx = threadIdx.x, ty = threadIdx.y;
    int t0 = blockIdx.x * 32, d0 = blockIdx.y * 32, bh = blockIdx.z;
    int b = bh >> 4, h = bh & 15;
#pragma unroll
    for (int j = 0; j < 4; j++)
        t[ty + 8*j][tx] = KVm[(size_t)(b*TKV + t0 + ty + 8*j) * 2048 + 1024 + h*HD + d0 + tx];
    __syncthreads();
#pragma unroll
    for (int j = 0; j < 4; j++)
        VT[((size_t)bh*HD + d0 + ty + 8*j) * TKV + t0 + tx] = t[tx][ty + 8*j];
}

// ------- split-precision GEMM: C = (Ah+Al) * (Bh+Bl)^T  (drops Al*Bl) -------
// 3 passes: Ah*Bh, Ah*Bl, Al*Bh. 128x128 tile, 4 waves, 16x16x32 MFMA.
// CT=float: write f32 C. CT=bf16: write hi to C; if Clo, write lo to Clo (cols<Nlo).
template <typename CT>
__global__ __launch_bounds__(256) void gemm3_bt(const bf16_t* __restrict__ Ah,
                                                const bf16_t* __restrict__ Al,
                                                const bf16_t* __restrict__ Bh,
                                                const bf16_t* __restrict__ Bl,
                                                CT* __restrict__ C,
                                                bf16_t* __restrict__ Clo,
                                                int M, int N, int K, int Nlo) {
    __shared__ bf16_t As[128 * 32];
    __shared__ bf16_t Bs[128 * 32];
    const int nbj = N >> 7;
    int bi = blockIdx.x / nbj, bj = blockIdx.x % nbj;
    int tid = threadIdx.x;
    int lane = tid & 63, w = tid >> 6;
    int wr = (w >> 1) * 64, wc = (w & 1) * 64;
    int lr = lane & 15, lg = lane >> 4;
    int row0 = tid >> 2, seg0 = tid & 3;

    f32x4_t acc[4][4];
#pragma unroll
    for (int m = 0; m < 4; m++)
#pragma unroll
        for (int n = 0; n < 4; n++)
            acc[m][n] = f32x4_t{0.f, 0.f, 0.f, 0.f};

    for (int p = 0; p < 3; ++p) {
        const bf16_t* Ap = (p < 2) ? Ah : Al;
        const bf16_t* Bp = (p == 1) ? Bl : Bh;
        for (int k0 = 0; k0 < K; k0 += 32) {
#pragma unroll
            for (int i = 0; i < 2; i++) {
                int row = row0 + i * 64;
                int sseg = seg0 ^ (row & 3);   // pre-swizzled global source, linear LDS dest
                gload16(Ap + (size_t)(bi*128 + row) * K + k0 + sseg*8, (void*)(As + row*32 + seg0*8));
                gload16(Bp + (size_t)(bj*128 + row) * K + k0 + sseg*8, (void*)(Bs + row*32 + seg0*8));
            }
            __syncthreads();
            bf16x8_t af[4], bfr[4];
#pragma unroll
            for (int m = 0; m < 4; m++) {
                int ra = wr + m*16 + lr;
                af[m]  = *(const bf16x8_t*)(As + ra*32 + ((lg ^ (ra & 3)) * 8));
                int rb = wc + m*16 + lr;
                bfr[m] = *(const bf16x8_t*)(Bs + rb*32 + ((lg ^ (rb & 3)) * 8));
            }
#pragma unroll
            for (int m = 0; m < 4; m++)
#pragma unroll
                for (int n = 0; n < 4; n++)
                    acc[m][n] = MFMA16(af[m], bfr[n], acc[m][n]);
            __syncthreads();
        }
    }
#pragma unroll
    for (int m = 0; m < 4; m++) {
        int r = bi*128 + wr + m*16 + lg*4;
#pragma unroll
        for (int n = 0; n < 4; n++) {
            int c = bj*128 + wc + n*16 + lr;
#pragma unroll
            for (int i = 0; i < 4; i++) {
                float v = acc[m][n][i];
                if constexpr (__is_same(CT, float)) {
                    C[(size_t)(r + i) * N + c] = v;
                } else {
                    bf16_t h = (bf16_t)v;
                    C[(size_t)(r + i) * N + c] = h;
                    if (Clo && c < Nlo)
                        Clo[(size_t)(r + i) * Nlo + c] = (bf16_t)(v - (float)h);
                }
            }
        }
    }
}

// ---------------- fused flash attention, split-precision logits ----------------
// grid: (Tq/64, B*H). block: 256 (4 waves x 16 q-rows). KV step = 32.
// logits = (q.kT + bias) * 8 computed via qh*kh + qh*kl + ql*kh; online softmax;
// P stored hi/lo; O = (Ph+Pl) V ; Y written as hi/lo bf16 [B*Tq][C].
__global__ __launch_bounds__(256) void attn_fwd2(const bf16_t* __restrict__ Qh,
                                                 const bf16_t* __restrict__ Ql,
                                                 const bf16_t* __restrict__ KVh,
                                                 const bf16_t* __restrict__ Kl,
                                                 const bf16_t* __restrict__ VT,
                                                 const float*  __restrict__ Bias,
                                                 bf16_t* __restrict__ Yh,
                                                 bf16_t* __restrict__ Yl) {
    __shared__ bf16_t pbh[4][16 * 40];   // per-wave P_hi tile, stride 40 (80B)
    __shared__ bf16_t pbl[4][16 * 40];   // per-wave P_lo tile
    int qt = blockIdx.x, bh = blockIdx.y;
    int b = bh >> 4, h = bh & 15;
    int tid = threadIdx.x, lane = tid & 63, w = tid >> 6;
    int lr = lane & 15, lg = lane >> 4;
    int q0 = qt * 64 + w * 16;

    const bf16_t* qph = Qh + (size_t)(b*TQ + q0 + lr) * CE + h*HD + lg*8;
    const bf16_t* qpl = Ql + (size_t)(b*TQ + q0 + lr) * CE + h*HD + lg*8;
    bf16x8_t qh0 = *(const bf16x8_t*)qph;          // d 0..31 chunk
    bf16x8_t qh1 = *(const bf16x8_t*)(qph + 32);   // d 32..63
    bf16x8_t ql0 = *(const bf16x8_t*)qpl;
    bf16x8_t ql1 = *(const bf16x8_t*)(qpl + 32);

    float m_r[4], l_r[4];
    f32x4_t oa[4];
#pragma unroll
    for (int i = 0; i < 4; i++) { m_r[i] = -1e30f; l_r[i] = 0.f; oa[i] = f32x4_t{0.f,0.f,0.f,0.f}; }

    bf16_t* myph = pbh[w];
    bf16_t* mypl = pbl[w];
    const float* bp = Bias + ((size_t)h*TQ + q0 + lg*4) * TKV + lr;
    const bf16_t* khbase = KVh + (size_t)(b*TKV) * 2048 + h*HD + lg*8;   // K = cols 0..1023
    const bf16_t* klbase = Kl  + (size_t)(b*TKV) * 1024 + h*HD + lg*8;
    const bf16_t* vbase  = VT + ((size_t)bh*HD + lr) * TKV + lg*8;

    for (int kv0 = 0; kv0 < TKV; kv0 += 32) {
        const bf16_t* kh = khbase + (size_t)(kv0 + lr) * 2048;
        const bf16_t* kl = klbase + (size_t)(kv0 + lr) * 1024;
        bf16x8_t khA0 = *(const bf16x8_t*)kh;
        bf16x8_t khA1 = *(const bf16x8_t*)(kh + 32);
        bf16x8_t khB0 = *(const bf16x8_t*)(kh + (size_t)16*2048);
        bf16x8_t khB1 = *(const bf16x8_t*)(kh + (size_t)16*2048 + 32);
        bf16x8_t klA0 = *(const bf16x8_t*)kl;
        bf16x8_t klA1 = *(const bf16x8_t*)(kl + 32);
        bf16x8_t klB0 = *(const bf16x8_t*)(kl + (size_t)16*1024);
        bf16x8_t klB1 = *(const bf16x8_t*)(kl + (size_t)16*1024 + 32);

        f32x4_t s0 = f32x4_t{0.f,0.f,0.f,0.f}, s1 = f32x4_t{0.f,0.f,0.f,0.f};
        s0 = MFMA16(qh0, khA0, s0);  s0 = MFMA16(qh1, khA1, s0);
        s0 = MFMA16(qh0, klA0, s0);  s0 = MFMA16(qh1, klA1, s0);
        s0 = MFMA16(ql0, khA0, s0);  s0 = MFMA16(ql1, khA1, s0);
        s1 = MFMA16(qh0, khB0, s1);  s1 = MFMA16(qh1, khB1, s1);
        s1 = MFMA16(qh0, klB0, s1);  s1 = MFMA16(qh1, klB1, s1);
        s1 = MFMA16(ql0, khB0, s1);  s1 = MFMA16(ql1, khB1, s1);

        float p0[4], p1[4], mx[4], sc[4], rs[4];
#pragma unroll
        for (int i = 0; i < 4; i++) {
            float b0 = bp[(size_t)i*TKV + kv0];
            float b1 = bp[(size_t)i*TKV + kv0 + 16];
            p0[i] = (s0[i] + b0) * 8.f;     // attn = (qk + bias) / SCALE, SCALE = 1/8
            p1[i] = (s1[i] + b1) * 8.f;
            mx[i] = fmaxf(p0[i], p1[i]);
        }
#pragma unroll
        for (int d = 1; d < 16; d <<= 1) {
#pragma unroll
            for (int i = 0; i < 4; i++) mx[i] = fmaxf(mx[i], __shfl_xor(mx[i], d));
        }
#pragma unroll
        for (int i = 0; i < 4; i++) {
            float mn = fmaxf(m_r[i], mx[i]);
            sc[i] = __expf(m_r[i] - mn);
            m_r[i] = mn;
            p0[i] = __expf(p0[i] - mn);
            p1[i] = __expf(p1[i] - mn);
            rs[i] = p0[i] + p1[i];
        }
#pragma unroll
        for (int d = 1; d < 16; d <<= 1) {
#pragma unroll
            for (int i = 0; i < 4; i++) rs[i] += __shfl_xor(rs[i], d);
        }
#pragma unroll
        for (int i = 0; i < 4; i++) l_r[i] = l_r[i] * sc[i] + rs[i];
#pragma unroll
        for (int c = 0; c < 4; c++)
#pragma unroll
            for (int i = 0; i < 4; i++) oa[c][i] *= sc[i];

        // P -> LDS as hi/lo (rows q=4*lg+i, cols k), read back as MFMA A-fragments
#pragma unroll
        for (int i = 0; i < 4; i++) {
            bf16_t h0 = (bf16_t)p0[i];
            bf16_t h1 = (bf16_t)p1[i];
            myph[(lg*4 + i)*40 + lr]      = h0;
            myph[(lg*4 + i)*40 + 16 + lr] = h1;
            mypl[(lg*4 + i)*40 + lr]      = (bf16_t)(p0[i] - (float)h0);
            mypl[(lg*4 + i)*40 + 16 + lr] = (bf16_t)(p1[i] - (float)h1);
        }
        bf16x8_t pah = *(const bf16x8_t*)(myph + lr*40 + lg*8);
        bf16x8_t pal = *(const bf16x8_t*)(mypl + lr*40 + lg*8);

        const bf16_t* vp = vbase + kv0;
#pragma unroll
        for (int c = 0; c < 4; c++) {
            bf16x8_t vf = *(const bf16x8_t*)(vp + (size_t)c*16*TKV);
            oa[c] = MFMA16(pah, vf, oa[c]);
            oa[c] = MFMA16(pal, vf, oa[c]);
        }
    }
#pragma unroll
    for (int c = 0; c < 4; c++)
#pragma unroll
        for (int i = 0; i < 4; i++) {
            float yv = oa[c][i] / l_r[i];
            bf16_t hh = (bf16_t)yv;
            size_t idx = (size_t)(b*TQ + q0 + lg*4 + i) * CE + h*HD + c*16 + lr;
            Yh[idx] = hh;
            Yl[idx] = (bf16_t)(yv - (float)hh);
        }
}

// ---------------- launch ----------------
extern "C" void kernel_launch(void* const* d_in, const int* in_sizes, int n_in,
                              void* d_out, int out_size, void* d_ws, size_t ws_size,
                              hipStream_t stream) {
    const float* x_q   = (const float*)d_in[0];
    const float* x_kv  = (const float*)d_in[1];
    const float* pbias = (const float*)d_in[2];
    const float* W_q   = (const float*)d_in[3];
    const float* W_kv  = (const float*)d_in[4];
    const float* W_pj  = (const float*)d_in[5];
    float* out = (float*)d_out;

    bf16_t* ws = (bf16_t*)d_ws;
    const size_t MEG = 1024 * 1024;   // bf16-element offsets
    bf16_t* xq_hi  = ws;              //  4M  (reused as y_hi after q GEMM)
    bf16_t* xq_lo  = ws + 4*MEG;      //  4M  (reused as y_lo)
    bf16_t* xkv_hi = ws + 8*MEG;      //  4M
    bf16_t* xkv_lo = ws + 12*MEG;     //  4M  (reused as vT after kv GEMM)
    bf16_t* wqT_h  = ws + 16*MEG;     //  1M
    bf16_t* wqT_l  = ws + 17*MEG;     //  1M
    bf16_t* wkvT_h = ws + 18*MEG;     //  2M
    bf16_t* wkvT_l = ws + 20*MEG;     //  2M
    bf16_t* wpT_h  = ws + 22*MEG;     //  1M
    bf16_t* wpT_l  = ws + 23*MEG;     //  1M
    bf16_t* q_hi   = ws + 24*MEG;     //  4M
    bf16_t* q_lo   = ws + 28*MEG;     //  4M
    bf16_t* kv_hi  = ws + 32*MEG;     //  8M  [4096][2048]
    bf16_t* k_lo   = ws + 40*MEG;     //  4M  [4096][1024]
    bf16_t* vT     = xkv_lo;          //  2M  [B*H][64][2048] (aliases xkv_lo, dead by then)
    bf16_t* y_hi   = xq_hi;           //  4M  (aliases xq, dead by then)
    bf16_t* y_lo   = xq_lo;

    dim3 tb(32, 8);
    cvt_split<<<1024, 256, 0, stream>>>(x_q,  xq_hi,  xq_lo,  (MQ*CE)/4);
    cvt_split<<<1024, 256, 0, stream>>>(x_kv, xkv_hi, xkv_lo, (MQ*CE)/4);
    wsplit_t<<<dim3(32, 32), tb, 0, stream>>>(W_q,  wqT_h,  wqT_l,  CE, CE);
    wsplit_t<<<dim3(64, 32), tb, 0, stream>>>(W_kv, wkvT_h, wkvT_l, CE, 2048);
    wsplit_t<<<dim3(32, 32), tb, 0, stream>>>(W_pj, wpT_h,  wpT_l,  CE, CE);

    gemm3_bt<bf16_t><<<(MQ/128)*(CE/128),   256, 0, stream>>>(
        xq_hi, xq_lo, wqT_h, wqT_l, q_hi, q_lo, MQ, CE, CE, CE);
    gemm3_bt<bf16_t><<<(MQ/128)*(2048/128), 256, 0, stream>>>(
        xkv_hi, xkv_lo, wkvT_h, wkvT_l, kv_hi, k_lo, MQ, 2048, CE, CE);

    vtrans<<<dim3(64, 2, 32), tb, 0, stream>>>(kv_hi, vT);

    attn_fwd2<<<dim3(TQ/64, NB*NH), 256, 0, stream>>>(
        q_hi, q_lo, kv_hi, k_lo, vT, pbias, y_hi, y_lo);

    gemm3_bt<float><<<(MQ/128)*(CE/128), 256, 0, stream>>>(
        y_hi, y_lo, wpT_h, wpT_l, out, nullptr, MQ, CE, CE, 0);
}

// Round 3
// 670.049 us; speedup vs baseline: 1.5138x; 1.5138x over previous
//
#include <hip/hip_runtime.h>
#include <hip/hip_bf16.h>

// Problem constants (fixed by setup_inputs)
#define TQ   2048
#define TKV  2048
#define NB   2
#define NH   16
#define HD   64
#define CE   1024          // n_embd
#define MQ   (NB*TQ)       // 4096 rows

typedef __bf16 bf16_t;
typedef __bf16 bf16x4_t __attribute__((ext_vector_type(4)));
typedef __bf16 bf16x8_t __attribute__((ext_vector_type(8)));
typedef float  f32x4_t  __attribute__((ext_vector_type(4)));

#define MFMA16(a,b,c) __builtin_amdgcn_mfma_f32_16x16x32_bf16((a),(b),(c),0,0,0)

__device__ __forceinline__ void gload16(const void* g, void* l) {
    __builtin_amdgcn_global_load_lds(
        (__attribute__((address_space(1))) void*)(void*)g,
        (__attribute__((address_space(3))) void*)l, 16, 0, 0);
}

// ---------------- f32 -> (hi,lo) bf16 split, vectorized x4 ----------------
__global__ __launch_bounds__(256) void cvt_split(const float* __restrict__ x,
                                                 bf16_t* __restrict__ hi,
                                                 bf16_t* __restrict__ lo, int n4) {
    int i = blockIdx.x * blockDim.x + threadIdx.x;
    int stride = gridDim.x * blockDim.x;
    for (; i < n4; i += stride) {
        f32x4_t v = ((const f32x4_t*)x)[i];
        bf16x4_t h, l;
#pragma unroll
        for (int j = 0; j < 4; j++) {
            h[j] = (bf16_t)v[j];
            l[j] = (bf16_t)(v[j] - (float)h[j]);
        }
        ((bf16x4_t*)hi)[i] = h;
        ((bf16x4_t*)lo)[i] = l;
    }
}

// ---- weight transpose+split: W f32 [K][N] -> Wh,Wl bf16 [N][K] ----
__global__ __launch_bounds__(256) void wsplit_t(const float* __restrict__ W,
                                                bf16_t* __restrict__ Wh,
                                                bf16_t* __restrict__ Wl, int K, int N) {
    __shared__ float t[32][33];
    int tx = threadIdx.x, ty = threadIdx.y;
    int n0 = blockIdx.x * 32, k0 = blockIdx.y * 32;
#pragma unroll
    for (int j = 0; j < 4; j++)
        t[ty + 8*j][tx] = W[(size_t)(k0 + ty + 8*j) * N + n0 + tx];
    __syncthreads();
#pragma unroll
    for (int j = 0; j < 4; j++) {
        float v = t[tx][ty + 8*j];
        bf16_t h = (bf16_t)v;
        Wh[(size_t)(n0 + ty + 8*j) * K + k0 + tx] = h;
        Wl[(size_t)(n0 + ty + 8*j) * K + k0 + tx] = (bf16_t)(v - (float)h);
    }
}

// ---- V transpose: kv_hi bf16 [B*Tkv][2048] (v = cols 1024..) -> VT [B*H][64][Tkv] ----
__global__ __launch_bounds__(256) void vtrans(const bf16_t* __restrict__ KVm,
                                              bf16_t* __restrict__ VT) {
    __shared__ bf16_t t[32][33];
    int tx = threadIdx.x, ty = threadIdx.y;
    int t0 = blockIdx.x * 32, d0 = blockIdx.y * 32, bh = blockIdx.z;
    int b = bh >> 4, h = bh & 15;
#pragma unroll
    for (int j = 0; j < 4; j++)
        t[ty + 8*j][tx] = KVm[(size_t)(b*TKV + t0 + ty + 8*j) * 2048 + 1024 + h*HD + d0 + tx];
    __syncthreads();
#pragma unroll
    for (int j = 0; j < 4; j++)
        VT[((size_t)bh*HD + d0 + ty + 8*j) * TKV + t0 + tx] = t[tx][ty + 8*j];
}

// ------- split-precision GEMM body: 128x128 tile, 4 waves, 16x16x32 MFMA -------
// PASSES=3: Ah*Bh + Ah*Bl + Al*Bh. PASSES=2: Ah*Bh + Al*Bh.
template <int PASSES, typename CT>
__device__ __forceinline__ void gemm_body(const bf16_t* __restrict__ Ah,
                                          const bf16_t* __restrict__ Al,
                                          const bf16_t* __restrict__ Bh,
                                          const bf16_t* __restrict__ Bl,
                                          CT* __restrict__ C,
                                          bf16_t* __restrict__ Clo,
                                          int bi, int bj, int N, int K, int Nlo,
                                          bf16_t* As, bf16_t* Bs, int tid) {
    int lane = tid & 63, w = tid >> 6;
    int wr = (w >> 1) * 64, wc = (w & 1) * 64;
    int lr = lane & 15, lg = lane >> 4;
    int row0 = tid >> 2, seg0 = tid & 3;

    f32x4_t acc[4][4];
#pragma unroll
    for (int m = 0; m < 4; m++)
#pragma unroll
        for (int n = 0; n < 4; n++)
            acc[m][n] = f32x4_t{0.f, 0.f, 0.f, 0.f};

    for (int p = 0; p < PASSES; ++p) {
        const bf16_t* Ap;
        const bf16_t* Bp;
        if (p == 0)      { Ap = Ah; Bp = Bh; }
        else if (p == 1) { if (PASSES == 3) { Ap = Ah; Bp = Bl; } else { Ap = Al; Bp = Bh; } }
        else             { Ap = Al; Bp = Bh; }
        for (int k0 = 0; k0 < K; k0 += 32) {
#pragma unroll
            for (int i = 0; i < 2; i++) {
                int row = row0 + i * 64;
                int sseg = seg0 ^ (row & 3);   // pre-swizzled global source, linear LDS dest
                gload16(Ap + (size_t)(bi*128 + row) * K + k0 + sseg*8, (void*)(As + row*32 + seg0*8));
                gload16(Bp + (size_t)(bj*128 + row) * K + k0 + sseg*8, (void*)(Bs + row*32 + seg0*8));
            }
            __syncthreads();
            bf16x8_t af[4], bfr[4];
#pragma unroll
            for (int m = 0; m < 4; m++) {
                int ra = wr + m*16 + lr;
                af[m]  = *(const bf16x8_t*)(As + ra*32 + ((lg ^ (ra & 3)) * 8));
                int rb = wc + m*16 + lr;
                bfr[m] = *(const bf16x8_t*)(Bs + rb*32 + ((lg ^ (rb & 3)) * 8));
            }
#pragma unroll
            for (int m = 0; m < 4; m++)
#pragma unroll
                for (int n = 0; n < 4; n++)
                    acc[m][n] = MFMA16(af[m], bfr[n], acc[m][n]);
            __syncthreads();
        }
    }
#pragma unroll
    for (int m = 0; m < 4; m++) {
        int r = bi*128 + wr + m*16 + lg*4;
#pragma unroll
        for (int n = 0; n < 4; n++) {
            int c = bj*128 + wc + n*16 + lr;
#pragma unroll
            for (int i = 0; i < 4; i++) {
                float v = acc[m][n][i];
                if constexpr (__is_same(CT, float)) {
                    C[(size_t)(r + i) * N + c] = v;
                } else {
                    bf16_t h = (bf16_t)v;
                    C[(size_t)(r + i) * N + c] = h;
                    if (Clo && c < Nlo)
                        Clo[(size_t)(r + i) * Nlo + c] = (bf16_t)(v - (float)h);
                }
            }
        }
    }
}

// Fused q-proj + kv-proj: blocks 0..255 -> q (32x8 tiles), 256..767 -> kv (32x16)
__global__ __launch_bounds__(256) void gemm_qkv(const bf16_t* xqh, const bf16_t* xql,
                                                const bf16_t* wqh, const bf16_t* wql,
                                                bf16_t* q_hi, bf16_t* q_lo,
                                                const bf16_t* xkh, const bf16_t* xkl,
                                                const bf16_t* wkh, const bf16_t* wkl,
                                                bf16_t* kv_hi, bf16_t* k_lo) {
    __shared__ bf16_t As[128 * 32];
    __shared__ bf16_t Bs[128 * 32];
    int id = blockIdx.x, tid = threadIdx.x;
    if (id < 256) {
        gemm_body<3, bf16_t>(xqh, xql, wqh, wql, q_hi, q_lo,
                             id >> 3, id & 7, CE, CE, CE, As, Bs, tid);
    } else {
        id -= 256;
        gemm_body<3, bf16_t>(xkh, xkl, wkh, wkl, kv_hi, k_lo,
                             id >> 4, id & 15, 2048, CE, CE, As, Bs, tid);
    }
}

// Out-projection: 2-pass (yh*Wh + yl*Wh), f32 output
__global__ __launch_bounds__(256) void gemm_proj(const bf16_t* yh, const bf16_t* yl,
                                                 const bf16_t* wph,
                                                 float* out) {
    __shared__ bf16_t As[128 * 32];
    __shared__ bf16_t Bs[128 * 32];
    int id = blockIdx.x, tid = threadIdx.x;
    gemm_body<2, float>(yh, yl, wph, nullptr, out, nullptr,
                        id >> 3, id & 7, CE, CE, 0, As, Bs, tid);
}

// ---------------- fused flash attention v3 ----------------
// grid: 512 = 16 qt x 32 bh (XCD-swizzled). block: 256 = 4 waves x 32 q-rows.
// KVBLK=64; K_hi/K_lo/V staged in LDS (XOR-seg swizzle both sides).
// logits = (q.kT + bias)*8 via qh*kh + qh*kl + ql*kh; online softmax with exact
// defer-max skip; PV with P_hi only; Y written hi/lo bf16.
__global__ __launch_bounds__(256, 2) void attn_fwd3(const bf16_t* __restrict__ Qh,
                                                    const bf16_t* __restrict__ Ql,
                                                    const bf16_t* __restrict__ KVh,
                                                    const bf16_t* __restrict__ Kl,
                                                    const bf16_t* __restrict__ VT,
                                                    const float*  __restrict__ Bias,
                                                    bf16_t* __restrict__ Yh,
                                                    bf16_t* __restrict__ Yl) {
    __shared__ bf16_t Kh_s[64 * 64];
    __shared__ bf16_t Kl_s[64 * 64];
    __shared__ bf16_t V_s [64 * 64];     // [d=64][kv=64]
    __shared__ bf16_t pb[4][32 * 72];    // per-wave P tile: 32 q rows, stride 72

    int id = blockIdx.x;
    int swz = (id & 7) * 64 + (id >> 3);     // XCD-contiguous: 2 heads per XCD
    int qt = swz & 15, bh = swz >> 4;
    int b = bh >> 4, h = bh & 15;
    int tid = threadIdx.x, lane = tid & 63, w = tid >> 6;
    int lr = lane & 15, lg = lane >> 4;
    int q0 = qt * 128 + w * 32;

    // Q fragments (2 q-sets of 16 rows)
    bf16x8_t qhf[2][2], qlf[2][2];
#pragma unroll
    for (int qs = 0; qs < 2; qs++) {
        const bf16_t* qp = Qh + (size_t)(b*TQ + q0 + qs*16 + lr) * CE + h*HD + lg*8;
        const bf16_t* qp2 = Ql + (size_t)(b*TQ + q0 + qs*16 + lr) * CE + h*HD + lg*8;
        qhf[qs][0] = *(const bf16x8_t*)qp;
        qhf[qs][1] = *(const bf16x8_t*)(qp + 32);
        qlf[qs][0] = *(const bf16x8_t*)qp2;
        qlf[qs][1] = *(const bf16x8_t*)(qp2 + 32);
    }

    float m_r[2][4], l_r[2][4];
    f32x4_t oa[2][4];
#pragma unroll
    for (int qs = 0; qs < 2; qs++)
#pragma unroll
        for (int i = 0; i < 4; i++) {
            m_r[qs][i] = -1e30f; l_r[qs][i] = 0.f;
            oa[qs][i] = f32x4_t{0.f, 0.f, 0.f, 0.f};
        }

    bf16_t* myp = pb[w];
    const float*  bbase = Bias + ((size_t)h*TQ + q0 + lg*4) * TKV + lr;
    const bf16_t* khg = KVh + (size_t)(b*TKV) * 2048 + h*HD;
    const bf16_t* klg = Kl  + (size_t)(b*TKV) * 1024 + h*HD;
    const bf16_t* vtg = VT  + (size_t)bh * HD * TKV;

    for (int kv0 = 0; kv0 < TKV; kv0 += 64) {
        // ---- stage K_hi, K_lo, V tiles (swizzled source, linear LDS dest) ----
#pragma unroll
        for (int s = 0; s < 2; s++) {
            int idx = s * 256 + tid;
            int row = idx >> 3;
            int sw  = (idx & 7) ^ (row & 7);
            gload16(khg + (size_t)(kv0 + row) * 2048 + sw*8, (void*)(Kh_s + idx*8));
            gload16(klg + (size_t)(kv0 + row) * 1024 + sw*8, (void*)(Kl_s + idx*8));
            gload16(vtg + (size_t)row * TKV + kv0 + sw*8,    (void*)(V_s  + idx*8));
        }
        // ---- bias loads (overlap with staging) ----
        float bv[2][4][4];
#pragma unroll
        for (int qs = 0; qs < 2; qs++)
#pragma unroll
            for (int i = 0; i < 4; i++)
#pragma unroll
                for (int g = 0; g < 4; g++)
                    bv[qs][g][i] = bbase[(size_t)(qs*16 + i) * TKV + kv0 + g*16];
        __syncthreads();

        // ---- K fragments from LDS ----
        bf16x8_t khf_[4][2], klf_[4][2];
#pragma unroll
        for (int g = 0; g < 4; g++) {
            int rb = (g*16 + lr) * 64, x = lr & 7;
            khf_[g][0] = *(const bf16x8_t*)(Kh_s + rb + ((lg     ^ x) * 8));
            khf_[g][1] = *(const bf16x8_t*)(Kh_s + rb + (((4+lg) ^ x) * 8));
            klf_[g][0] = *(const bf16x8_t*)(Kl_s + rb + ((lg     ^ x) * 8));
            klf_[g][1] = *(const bf16x8_t*)(Kl_s + rb + (((4+lg) ^ x) * 8));
        }
        // ---- QK^T (3-pass split precision) ----
        f32x4_t sg[2][4];
#pragma unroll
        for (int qs = 0; qs < 2; qs++)
#pragma unroll
            for (int g = 0; g < 4; g++) {
                f32x4_t s = f32x4_t{0.f, 0.f, 0.f, 0.f};
                s = MFMA16(qhf[qs][0], khf_[g][0], s);
                s = MFMA16(qhf[qs][1], khf_[g][1], s);
                s = MFMA16(qlf[qs][0], khf_[g][0], s);
                s = MFMA16(qlf[qs][1], khf_[g][1], s);
                s = MFMA16(qhf[qs][0], klf_[g][0], s);
                s = MFMA16(qhf[qs][1], klf_[g][1], s);
                sg[qs][g] = s;
            }

        // ---- online softmax ----
        float p[2][4][4], mx[2][4], mn_[2][4];
        int grow = 0;
#pragma unroll
        for (int qs = 0; qs < 2; qs++)
#pragma unroll
            for (int i = 0; i < 4; i++) {
                float a0 = (sg[qs][0][i] + bv[qs][0][i]) * 8.f;
                float a1 = (sg[qs][1][i] + bv[qs][1][i]) * 8.f;
                float a2 = (sg[qs][2][i] + bv[qs][2][i]) * 8.f;
                float a3 = (sg[qs][3][i] + bv[qs][3][i]) * 8.f;
                p[qs][0][i] = a0; p[qs][1][i] = a1; p[qs][2][i] = a2; p[qs][3][i] = a3;
                mx[qs][i] = fmaxf(fmaxf(a0, a1), fmaxf(a2, a3));
            }
#pragma unroll
        for (int d = 1; d < 16; d <<= 1)
#pragma unroll
            for (int qs = 0; qs < 2; qs++)
#pragma unroll
                for (int i = 0; i < 4; i++)
                    mx[qs][i] = fmaxf(mx[qs][i], __shfl_xor(mx[qs][i], d));
#pragma unroll
        for (int qs = 0; qs < 2; qs++)
#pragma unroll
            for (int i = 0; i < 4; i++) {
                mn_[qs][i] = fmaxf(m_r[qs][i], mx[qs][i]);
                grow |= (mn_[qs][i] > m_r[qs][i]) ? 1 : 0;
            }
        if (__any(grow)) {
#pragma unroll
            for (int qs = 0; qs < 2; qs++)
#pragma unroll
                for (int i = 0; i < 4; i++) {
                    float sc = __expf(m_r[qs][i] - mn_[qs][i]);
                    m_r[qs][i] = mn_[qs][i];
                    l_r[qs][i] *= sc;
#pragma unroll
                    for (int c = 0; c < 4; c++) oa[qs][c][i] *= sc;
                }
        }
        float rs[2][4];
#pragma unroll
        for (int qs = 0; qs < 2; qs++)
#pragma unroll
            for (int i = 0; i < 4; i++) {
                float r = 0.f;
#pragma unroll
                for (int g = 0; g < 4; g++) {
                    p[qs][g][i] = __expf(p[qs][g][i] - m_r[qs][i]);
                    r += p[qs][g][i];
                }
                rs[qs][i] = r;
            }
#pragma unroll
        for (int d = 1; d < 16; d <<= 1)
#pragma unroll
            for (int qs = 0; qs < 2; qs++)
#pragma unroll
                for (int i = 0; i < 4; i++)
                    rs[qs][i] += __shfl_xor(rs[qs][i], d);
#pragma unroll
        for (int qs = 0; qs < 2; qs++)
#pragma unroll
            for (int i = 0; i < 4; i++)
                l_r[qs][i] += rs[qs][i];

        // ---- P -> LDS (wave-private), read back as A-fragments ----
#pragma unroll
        for (int qs = 0; qs < 2; qs++)
#pragma unroll
            for (int i = 0; i < 4; i++)
#pragma unroll
                for (int g = 0; g < 4; g++)
                    myp[(qs*16 + lg*4 + i)*72 + g*16 + lr] = (bf16_t)p[qs][g][i];
        bf16x8_t pa[2][2];
#pragma unroll
        for (int qs = 0; qs < 2; qs++) {
            pa[qs][0] = *(const bf16x8_t*)(myp + (qs*16 + lr)*72 + lg*8);
            pa[qs][1] = *(const bf16x8_t*)(myp + (qs*16 + lr)*72 + 32 + lg*8);
        }
        // ---- PV ----
#pragma unroll
        for (int c = 0; c < 4; c++) {
            int r = c*16 + lr, x = r & 7;
            bf16x8_t vf0 = *(const bf16x8_t*)(V_s + r*64 + ((lg     ^ x) * 8));
            bf16x8_t vf1 = *(const bf16x8_t*)(V_s + r*64 + (((4+lg) ^ x) * 8));
#pragma unroll
            for (int qs = 0; qs < 2; qs++) {
                oa[qs][c] = MFMA16(pa[qs][0], vf0, oa[qs][c]);
                oa[qs][c] = MFMA16(pa[qs][1], vf1, oa[qs][c]);
            }
        }
        __syncthreads();
    }

    // ---- epilogue: Y = O / l, written hi/lo ----
#pragma unroll
    for (int qs = 0; qs < 2; qs++)
#pragma unroll
        for (int c = 0; c < 4; c++)
#pragma unroll
            for (int i = 0; i < 4; i++) {
                float yv = oa[qs][c][i] / l_r[qs][i];
                bf16_t hh = (bf16_t)yv;
                size_t idx = (size_t)(b*TQ + q0 + qs*16 + lg*4 + i) * CE + h*HD + c*16 + lr;
                Yh[idx] = hh;
                Yl[idx] = (bf16_t)(yv - (float)hh);
            }
}

// ---------------- launch ----------------
extern "C" void kernel_launch(void* const* d_in, const int* in_sizes, int n_in,
                              void* d_out, int out_size, void* d_ws, size_t ws_size,
                              hipStream_t stream) {
    const float* x_q   = (const float*)d_in[0];
    const float* x_kv  = (const float*)d_in[1];
    const float* pbias = (const float*)d_in[2];
    const float* W_q   = (const float*)d_in[3];
    const float* W_kv  = (const float*)d_in[4];
    const float* W_pj  = (const float*)d_in[5];
    float* out = (float*)d_out;

    bf16_t* ws = (bf16_t*)d_ws;
    const size_t MEG = 1024 * 1024;   // bf16-element offsets
    bf16_t* xq_hi  = ws;              //  4M  (reused as y_hi after q GEMM)
    bf16_t* xq_lo  = ws + 4*MEG;      //  4M  (reused as y_lo)
    bf16_t* xkv_hi = ws + 8*MEG;      //  4M
    bf16_t* xkv_lo = ws + 12*MEG;     //  4M  (reused as vT after kv GEMM)
    bf16_t* wqT_h  = ws + 16*MEG;     //  1M
    bf16_t* wqT_l  = ws + 17*MEG;     //  1M
    bf16_t* wkvT_h = ws + 18*MEG;     //  2M
    bf16_t* wkvT_l = ws + 20*MEG;     //  2M
    bf16_t* wpT_h  = ws + 22*MEG;     //  1M
    bf16_t* wpT_l  = ws + 23*MEG;     //  1M
    bf16_t* q_hi   = ws + 24*MEG;     //  4M
    bf16_t* q_lo   = ws + 28*MEG;     //  4M
    bf16_t* kv_hi  = ws + 32*MEG;     //  8M  [4096][2048]
    bf16_t* k_lo   = ws + 40*MEG;     //  4M  [4096][1024]
    bf16_t* vT     = xkv_lo;          //  2M  [B*H][64][2048] (aliases xkv_lo, dead by then)
    bf16_t* y_hi   = xq_hi;           //  4M  (aliases xq, dead by then)
    bf16_t* y_lo   = xq_lo;

    dim3 tb(32, 8);
    cvt_split<<<1024, 256, 0, stream>>>(x_q,  xq_hi,  xq_lo,  (MQ*CE)/4);
    cvt_split<<<1024, 256, 0, stream>>>(x_kv, xkv_hi, xkv_lo, (MQ*CE)/4);
    wsplit_t<<<dim3(32, 32), tb, 0, stream>>>(W_q,  wqT_h,  wqT_l,  CE, CE);
    wsplit_t<<<dim3(64, 32), tb, 0, stream>>>(W_kv, wkvT_h, wkvT_l, CE, 2048);
    wsplit_t<<<dim3(32, 32), tb, 0, stream>>>(W_pj, wpT_h,  wpT_l,  CE, CE);

    gemm_qkv<<<768, 256, 0, stream>>>(xq_hi, xq_lo, wqT_h, wqT_l, q_hi, q_lo,
                                      xkv_hi, xkv_lo, wkvT_h, wkvT_l, kv_hi, k_lo);

    vtrans<<<dim3(64, 2, 32), tb, 0, stream>>>(kv_hi, vT);

    attn_fwd3<<<512, 256, 0, stream>>>(q_hi, q_lo, kv_hi, k_lo, vT, pbias, y_hi, y_lo);

    gemm_proj<<<256, 256, 0, stream>>>(y_hi, y_lo, wpT_h, out);
}